// Round 8
// baseline (427.217 us; speedup 1.0000x reference)
//
#include <hip/hip_runtime.h>
#include <hip/hip_bf16.h>

#define IN_C 128
#define HID_C 128
#define OUT_C 64

typedef unsigned short u16;
typedef unsigned int   u32;
typedef __attribute__((ext_vector_type(8))) short short8;
typedef __attribute__((ext_vector_type(4))) float f32x4;
typedef __attribute__((ext_vector_type(2))) float f32x2;

__device__ __forceinline__ u16 bf16_bits(float x) {
    __hip_bfloat16 h = __float2bfloat16(x);   // RNE
    return *(u16*)&h;
}
__device__ __forceinline__ void split_hi_lo(float a, u16& hi, u16& lo) {
    __hip_bfloat16 h = __float2bfloat16(a);
    float hf = __bfloat162float(h);
    __hip_bfloat16 l = __float2bfloat16(a - hf);
    hi = *(u16*)&h; lo = *(u16*)&l;
}
// acc.{x,y} += unpacked bf16 pair (packed f32 add: 1 VALU inst, same add order)
__device__ __forceinline__ void pk_acc(f32x2& acc, u32 v) {
    f32x2 val;
    val.x = __uint_as_float(v << 16);
    val.y = __uint_as_float(v & 0xffff0000u);
    asm("v_pk_add_f32 %0, %0, %1" : "+v"(acc) : "v"(val));
}

// ============================ CSR build: contention-free radix partition
// Buckets of 256 nodes: bucket = v>>8, K = ceil(N/256). NB partition blocks.

__global__ __launch_bounds__(256)
void part_hist(const int* __restrict__ keys, int* __restrict__ bh,
               int E, int K, int NB) {
    const int b = blockIdx.x;
    extern __shared__ int lh[];                 // K ints
    for (int i = threadIdx.x; i < K; i += 256) lh[i] = 0;
    __syncthreads();
    const int lo = (int)((long long)E * b / NB);
    const int hi = (int)((long long)E * (b + 1) / NB);
    for (int i = lo + threadIdx.x; i < hi; i += 256)
        atomicAdd(&lh[keys[i] >> 8], 1);        // LDS atomic
    __syncthreads();
    for (int k = threadIdx.x; k < K; k += 256)
        bh[k * NB + b] = lh[k];
}

template <bool PACK>
__global__ __launch_bounds__(256)
void part_scatter(const int* __restrict__ keys, const int* __restrict__ other,
                  const int* __restrict__ ofs, u32* __restrict__ out,
                  int E, int K, int NB) {
    const int b = blockIdx.x;
    extern __shared__ int lcur[];               // K ints
    for (int k = threadIdx.x; k < K; k += 256) lcur[k] = ofs[k * NB + b];
    __syncthreads();
    const int lo = (int)((long long)E * b / NB);
    const int hi = (int)((long long)E * (b + 1) / NB);
    for (int i = lo + threadIdx.x; i < hi; i += 256) {
        int key = keys[i];
        int p = atomicAdd(&lcur[key >> 8], 1);  // LDS atomic
        out[p] = PACK ? (((u32)other[i] << 8) | (u32)(key & 255)) : (u32)key;
    }
}

__global__ __launch_bounds__(256)
void bucket_count(const u32* __restrict__ pairs, const int* __restrict__ ofs,
                  int* __restrict__ cnt, int N, int NB, int K, int cap) {
    const int k = blockIdx.x;
    __shared__ int lc[256];
    lc[threadIdx.x] = 0;
    __syncthreads();
    const int s0 = ofs[k * NB];
    const int s1 = (k == K - 1) ? cap : ofs[(k + 1) * NB];
    for (int i = s0 + threadIdx.x; i < s1; i += 256)
        atomicAdd(&lc[pairs[i] & 255], 1);
    __syncthreads();
    const int node = k * 256 + threadIdx.x;
    if (node < N) cnt[node] = lc[threadIdx.x];
}

__global__ __launch_bounds__(256)
void bucket_fill(const u32* __restrict__ pairs, const int* __restrict__ ofs,
                 const int* __restrict__ row_start, int* __restrict__ csr,
                 int N, int NB, int K, int E) {
    const int k = blockIdx.x;
    __shared__ int lcur[256];
    const int node = k * 256 + threadIdx.x;
    lcur[threadIdx.x] = (node < N) ? row_start[node] : 0;
    __syncthreads();
    const int s0 = ofs[k * NB];
    const int s1 = (k == K - 1) ? E : ofs[(k + 1) * NB];
    for (int i = s0 + threadIdx.x; i < s1; i += 256) {
        u32 pr = pairs[i];
        int p = atomicAdd(&lcur[pr & 255], 1);
        csr[p] = (int)(pr >> 8);
    }
}

// ============================ generic scans

__global__ __launch_bounds__(256)
void scan_pass1(const int* __restrict__ in, int* __restrict__ blocksum, int M) {
    const int b = blockIdx.x, t = threadIdx.x;
    const int base = b * 1024 + t * 4;
    int s = 0;
#pragma unroll
    for (int j = 0; j < 4; ++j) {
        int idx = base + j;
        if (idx < M) s += in[idx];
    }
#pragma unroll
    for (int off = 32; off >= 1; off >>= 1) s += __shfl_xor(s, off);
    __shared__ int wsum[4];
    if ((t & 63) == 0) wsum[t >> 6] = s;
    __syncthreads();
    if (t == 0) blocksum[b] = wsum[0] + wsum[1] + wsum[2] + wsum[3];
}

__global__ __launch_bounds__(1024)
void scan_g2(int* __restrict__ a, int nb) {
    __shared__ int s[1024];
    const int t = threadIdx.x;
    int v = (t < nb) ? a[t] : 0;
    s[t] = v;
    __syncthreads();
    for (int off = 1; off < 1024; off <<= 1) {
        int x = (t >= off) ? s[t - off] : 0;
        __syncthreads();
        s[t] += x;
        __syncthreads();
    }
    if (t < nb) a[t] = s[t] - v;    // exclusive
}

__global__ __launch_bounds__(256)
void scan_g3(const int* __restrict__ in, const int* __restrict__ blockoff,
             int* __restrict__ out, int M) {
    __shared__ int ssum[256];
    const int b = blockIdx.x, t = threadIdx.x;
    const int base = b * 1024 + t * 4;
    int c[4];
#pragma unroll
    for (int j = 0; j < 4; ++j) {
        int idx = base + j;
        c[j] = (idx < M) ? in[idx] : 0;
    }
    const int tot = c[0] + c[1] + c[2] + c[3];
    ssum[t] = tot;
    __syncthreads();
    for (int off = 1; off < 256; off <<= 1) {
        int v = (t >= off) ? ssum[t - off] : 0;
        __syncthreads();
        ssum[t] += v;
        __syncthreads();
    }
    int run = blockoff[b] + ssum[t] - tot;
#pragma unroll
    for (int j = 0; j < 4; ++j) {
        int idx = base + j;
        if (idx < M) { out[idx] = run; run += c[j]; }
    }
}

__global__ __launch_bounds__(256)
void scan_pass3n(const int* __restrict__ cnt_in, const int* __restrict__ cnt_out,
                 const int* __restrict__ blockoff, int* __restrict__ row_start,
                 float* __restrict__ iso, float* __restrict__ isi, int N, int E) {
    __shared__ int ssum[256];
    const int b = blockIdx.x, t = threadIdx.x;
    const int base = b * 1024 + t * 4;
    int c[4];
#pragma unroll
    for (int j = 0; j < 4; ++j) {
        int idx = base + j;
        c[j] = (idx < N) ? cnt_in[idx] : 0;
    }
    const int tot = c[0] + c[1] + c[2] + c[3];
    ssum[t] = tot;
    __syncthreads();
    for (int off = 1; off < 256; off <<= 1) {
        int v = (t >= off) ? ssum[t - off] : 0;
        __syncthreads();
        ssum[t] += v;
        __syncthreads();
    }
    int run = blockoff[b] + ssum[t] - tot;
#pragma unroll
    for (int j = 0; j < 4; ++j) {
        int idx = base + j;
        if (idx < N) {
            row_start[idx] = run;
            run += c[j];
            int di = c[j] < 1 ? 1 : c[j];
            int co = cnt_out[idx];
            int dd = co < 1 ? 1 : co;
            isi[idx] = rsqrtf((float)di);
            iso[idx] = rsqrtf((float)dd);
        }
    }
    if (b == 0 && t == 0) row_start[N] = E;
}

// ============================ weight prep: Wt[c][k] = bf16(W[k][c])

__global__ __launch_bounds__(128)
void wt_prep_all(const float* __restrict__ W1, const float* __restrict__ W2,
                 const float* __restrict__ W3, u16* __restrict__ Wt1,
                 u16* __restrict__ Wt2, u16* __restrict__ Wt3) {
    const int b = blockIdx.x, k = threadIdx.x;
    if (b < 128)       Wt1[b * 128 + k] = bf16_bits(W1[k * 128 + b]);
    else if (b < 256)  { int c = b - 128; Wt2[c * 128 + k] = bf16_bits(W2[k * 128 + c]); }
    else               { int c = b - 256; Wt3[c * 128 + k] = bf16_bits(W3[k * 64 + c]); }
}

// ============================ shared MFMA phase
// sAh/sAl: 64 rows x 128 bf16, row stride 136. Wt: [C][128] bf16.
// Layout (HW-verified rounds 6-7): A row=lane&15, k=(lane>>4)*8+j;
// B col=lane&15; D col=lane&15, row=(lane>>4)*4+reg.
template <int C>
__device__ __forceinline__
void mfma_store(const u16* sAh, const u16* sAl, const u16* __restrict__ Wt,
                u16* __restrict__ H, int row0, int N, int t) {
    constexpr int NT = C / 16;
    const int wid = t >> 6, lane = t & 63;
    const int r0 = wid * 16;
    const int arow = r0 + (lane & 15);
    const int kb = (lane >> 4) * 8;

    f32x4 acc[NT];
#pragma unroll
    for (int i = 0; i < NT; ++i) acc[i] = (f32x4){0.f, 0.f, 0.f, 0.f};

    const u16* wbase = Wt + (size_t)(lane & 15) * 128 + kb;

#pragma unroll
    for (int kk = 0; kk < 4; ++kk) {
        short8 ah = *(const short8*)(&sAh[arow * 136 + kk * 32 + kb]);
        short8 al = *(const short8*)(&sAl[arow * 136 + kk * 32 + kb]);
#pragma unroll
        for (int ct = 0; ct < NT; ++ct) {
            short8 bf = *(const short8*)(wbase + ct * 16 * 128 + kk * 32);
            acc[ct] = __builtin_amdgcn_mfma_f32_16x16x32_bf16(ah, bf, acc[ct], 0, 0, 0);
            acc[ct] = __builtin_amdgcn_mfma_f32_16x16x32_bf16(al, bf, acc[ct], 0, 0, 0);
        }
    }

    const int rbase = row0 + r0 + (lane >> 4) * 4;
#pragma unroll
    for (int ct = 0; ct < NT; ++ct) {
        int gcol = ct * 16 + (lane & 15);
#pragma unroll
        for (int r = 0; r < 4; ++r) {
            int grow = rbase + r;
            if (grow < N) H[(size_t)grow * C + gcol] = bf16_bits(acc[ct][r]);
        }
    }
}

// ============================ gather helper (128-col bf16 rows, MLP-8)

__device__ __forceinline__
f32x2 gather128(const u16* __restrict__ Hin, const int* __restrict__ csr_src,
                int rs, int re, int lane) {
    f32x2 acc; acc.x = 0.f; acc.y = 0.f;
    int e = rs;
    while (e < re) {
        int nloc = re - e;
        if (nloc > 64) nloc = 64;
        int idx = (lane < nloc) ? csr_src[e + lane] : 0;
        int j = 0;
        for (; j + 8 <= nloc; j += 8) {
            u32 v[8];
#pragma unroll
            for (int q = 0; q < 8; ++q) {
                int s = __builtin_amdgcn_readlane(idx, j + q);
                v[q] = *(const u32*)(Hin + (size_t)s * 128 + lane * 2);
            }
#pragma unroll
            for (int q = 0; q < 8; ++q) pk_acc(acc, v[q]);
        }
        for (; j + 4 <= nloc; j += 4) {
            u32 v[4];
#pragma unroll
            for (int q = 0; q < 4; ++q) {
                int s = __builtin_amdgcn_readlane(idx, j + q);
                v[q] = *(const u32*)(Hin + (size_t)s * 128 + lane * 2);
            }
#pragma unroll
            for (int q = 0; q < 4; ++q) pk_acc(acc, v[q]);
        }
        for (; j < nloc; ++j) {
            int s = __builtin_amdgcn_readlane(idx, j);
            pk_acc(acc, *(const u32*)(Hin + (size_t)s * 128 + lane * 2));
        }
        e += nloc;
    }
    return acc;
}

// ============================ fused layer-1 GEMM (absorbs x_prep)
// H[N x 128] (bf16) = (features * iso[:,None]) @ W1, via hi/lo split planes.

__global__ __launch_bounds__(256)
void gemm1_fused(const float* __restrict__ X, const float* __restrict__ iso,
                 const u16* __restrict__ Wt, u16* __restrict__ H, int N) {
    __shared__ u16 sAh[64 * 136];
    __shared__ u16 sAl[64 * 136];
    const int t = threadIdx.x;
    const int row0 = blockIdx.x * 64;

    for (int i = t; i < 2048; i += 256) {       // 64 rows x 32 float4-chunks
        int r = i >> 5, kv = (i & 31) << 2;
        int gr = row0 + r;
        if (gr >= N) gr = N - 1;
        float s = iso[gr];
        float4 x = *(const float4*)(X + (size_t)gr * 128 + kv);
        u16 h0, l0, h1, l1, h2, l2, h3, l3;
        split_hi_lo(x.x * s, h0, l0);
        split_hi_lo(x.y * s, h1, l1);
        split_hi_lo(x.z * s, h2, l2);
        split_hi_lo(x.w * s, h3, l3);
        uint2 hp = make_uint2((u32)h0 | ((u32)h1 << 16), (u32)h2 | ((u32)h3 << 16));
        uint2 lp = make_uint2((u32)l0 | ((u32)l1 << 16), (u32)l2 | ((u32)l3 << 16));
        *(uint2*)(&sAh[r * 136 + kv]) = hp;
        *(uint2*)(&sAl[r * 136 + kv]) = lp;
    }
    __syncthreads();
    mfma_store<128>(sAh, sAl, Wt, H, row0, N, t);
}

// ============================ fused agg(prev layer) + GEMM(next layer)
// Per block: 4 waves gather 64 nodes (16/wave) from Hin via CSR, apply
// relu+bias+isi, scale by iso, split hi/lo into LDS, then MFMA with Wt.

template <int C>
__global__ __launch_bounds__(256)
void agg_gemm(const u16* __restrict__ Hin, const int* __restrict__ row_start,
              const int* __restrict__ csr_src, const float* __restrict__ isi,
              const float* __restrict__ iso, const float* __restrict__ bias,
              const u16* __restrict__ Wt, u16* __restrict__ Hout, int N) {
    __shared__ u16 sAh[64 * 136];
    __shared__ u16 sAl[64 * 136];
    const int t = threadIdx.x, wid = t >> 6, lane = t & 63;
    const int row0 = blockIdx.x * 64;
    const float2 b2 = *(const float2*)(bias + lane * 2);

    for (int i = 0; i < 16; ++i) {
        int r = wid * 16 + i;
        int n = row0 + r;
        if (n < N) {
            int rs = row_start[n], re = row_start[n + 1];
            f32x2 acc = gather128(Hin, csr_src, rs, re, lane);
            float sc = isi[n], so = iso[n];
            float o0 = fmaxf(acc.x * sc + b2.x, 0.f) * so;
            float o1 = fmaxf(acc.y * sc + b2.y, 0.f) * so;
            u16 h0, l0, h1, l1;
            split_hi_lo(o0, h0, l0);
            split_hi_lo(o1, h1, l1);
            *(u32*)(&sAh[r * 136 + lane * 2]) = (u32)h0 | ((u32)h1 << 16);
            *(u32*)(&sAl[r * 136 + lane * 2]) = (u32)l0 | ((u32)l1 << 16);
        }
    }
    __syncthreads();
    mfma_store<C>(sAh, sAl, Wt, Hout, row0, N, t);
}

// ============================ final aggregation: 64-col gather + log_softmax

__global__ __launch_bounds__(256)
void agg_final(const u16* __restrict__ H, const int* __restrict__ row_start,
               const int* __restrict__ csr_src, const float* __restrict__ isi,
               const float* __restrict__ bias, float* __restrict__ Out, int N) {
    const int wid  = (int)((blockIdx.x * (size_t)blockDim.x + threadIdx.x) >> 6);
    const int lane = threadIdx.x & 63;
    if (wid >= N) return;
    const int rs = row_start[wid];
    const int re = row_start[wid + 1];
    const float sc = isi[wid];

    float a = 0.f;
    int e = rs;
    while (e < re) {
        int nloc = re - e;
        if (nloc > 64) nloc = 64;
        int idx = (lane < nloc) ? csr_src[e + lane] : 0;
        int j = 0;
        for (; j + 8 <= nloc; j += 8) {
            u32 v[8];
#pragma unroll
            for (int q = 0; q < 8; ++q) {
                int s = __builtin_amdgcn_readlane(idx, j + q);
                v[q] = H[(size_t)s * 64 + lane];
            }
#pragma unroll
            for (int q = 0; q < 8; ++q) a += __uint_as_float(v[q] << 16);
        }
        for (; j + 4 <= nloc; j += 4) {
            u32 v[4];
#pragma unroll
            for (int q = 0; q < 4; ++q) {
                int s = __builtin_amdgcn_readlane(idx, j + q);
                v[q] = H[(size_t)s * 64 + lane];
            }
#pragma unroll
            for (int q = 0; q < 4; ++q) a += __uint_as_float(v[q] << 16);
        }
        for (; j < nloc; ++j) {
            int s = __builtin_amdgcn_readlane(idx, j);
            a += __uint_as_float((u32)H[(size_t)s * 64 + lane] << 16);
        }
        e += nloc;
    }
    float v = a * sc + bias[lane];
    float m = v;
#pragma unroll
    for (int off = 32; off >= 1; off >>= 1) m = fmaxf(m, __shfl_xor(m, off));
    float ex = expf(v - m);
    float ss = ex;
#pragma unroll
    for (int off = 32; off >= 1; off >>= 1) ss += __shfl_xor(ss, off);
    v = (v - m) - logf(ss);
    Out[(size_t)wid * 64 + lane] = v;
}

// ============================ launch

extern "C" void kernel_launch(void* const* d_in, const int* in_sizes, int n_in,
                              void* d_out, int out_size, void* d_ws, size_t ws_size,
                              hipStream_t stream) {
    const float* features = (const float*)d_in[0];
    const int*   src      = (const int*)d_in[1];
    const int*   dst      = (const int*)d_in[2];
    const float* W1       = (const float*)d_in[3];
    const float* b1       = (const float*)d_in[4];
    const float* W2       = (const float*)d_in[5];
    const float* b2       = (const float*)d_in[6];
    const float* W3       = (const float*)d_in[7];
    const float* b3       = (const float*)d_in[8];
    float*       out      = (float*)d_out;

    const int N  = in_sizes[0] / IN_C;   // 100000
    const int E  = in_sizes[1];          // 1600000
    const int K  = (N + 255) >> 8;       // 391 buckets of 256 nodes
    const int NB = 256;                  // partition blocks
    const int M  = 2 * K * NB;           // concat hist size (dst part | src part)
    const int nbe = (M + 1023) / 1024;
    const int nb  = (N + 1023) / 1024;

    char* ws = (char*)d_ws;
    const size_t SLOT = 400128;          // >= (N+1)*4, 128B-aligned
    int*   cnt_out   = (int*)(ws + 0 * SLOT);
    int*   cnt_in    = (int*)(ws + 1 * SLOT);
    int*   row_start = (int*)(ws + 2 * SLOT);
    float* iso       = (float*)(ws + 3 * SLOT);
    float* isi       = (float*)(ws + 4 * SLOT);
    int*   blocksum  = (int*)(ws + 5 * SLOT);
    int*   eblocksum = blocksum + 2048;
    int*   csr       = (int*)(ws + 6 * SLOT);            // E ints (6.4MB)
    char*  p         = ws + 6 * SLOT + 6400000;
    int*   BH        = (int*)p;                          // 800KB
    int*   OFS       = (int*)(p + 1000000);              // 800KB
    u32*   pairs     = (u32*)(p + 2000000);              // 2E u32 (12.8MB)
    u16*   Hb1       = (u16*)(p + 14800000);             // N*128 bf16 (25.6MB)
    u16*   Hb2       = (u16*)(p + 40400000);             // N*128 bf16 (25.6MB)
    u16*   Wt1       = (u16*)(p + 66000000);             // 128*128 bf16
    u16*   Wt2       = Wt1 + 128 * 128;
    u16*   Wt3       = Wt2 + 128 * 128;                  // 64*128 bf16

    const size_t ldsK = (size_t)K * sizeof(int);

    // ---- CSR build: deterministic two-array radix partition ----
    part_hist<<<NB, 256, ldsK, stream>>>(dst, BH,           E, K, NB);
    part_hist<<<NB, 256, ldsK, stream>>>(src, BH + K * NB,  E, K, NB);
    scan_pass1<<<nbe, 256, 0, stream>>>(BH, eblocksum, M);
    scan_g2<<<1, 1024, 0, stream>>>(eblocksum, nbe);
    scan_g3<<<nbe, 256, 0, stream>>>(BH, eblocksum, OFS, M);
    part_scatter<true ><<<NB, 256, ldsK, stream>>>(dst, src, OFS,          pairs, E, K, NB);
    part_scatter<false><<<NB, 256, ldsK, stream>>>(src, src, OFS + K * NB, pairs, E, K, NB);
    bucket_count<<<K, 256, 0, stream>>>(pairs, OFS,          cnt_in,  N, NB, K, E);
    bucket_count<<<K, 256, 0, stream>>>(pairs, OFS + K * NB, cnt_out, N, NB, K, 2 * E);
    scan_pass1<<<nb, 256, 0, stream>>>(cnt_in, blocksum, N);
    scan_g2<<<1, 1024, 0, stream>>>(blocksum, nb);
    scan_pass3n<<<nb, 256, 0, stream>>>(cnt_in, cnt_out, blocksum, row_start, iso, isi, N, E);
    bucket_fill<<<K, 256, 0, stream>>>(pairs, OFS, row_start, csr, N, NB, K, E);

    // ---- weights ----
    wt_prep_all<<<320, 128, 0, stream>>>(W1, W2, W3, Wt1, Wt2, Wt3);

    // ---- 3-layer GCN (fused agg->gemm) ----
    const int gblocks = (N + 63) / 64;
    const int ablocks = (int)(((size_t)N * 64 + 255) / 256);

    gemm1_fused<<<gblocks, 256, 0, stream>>>(features, iso, Wt1, Hb1, N);
    agg_gemm<128><<<gblocks, 256, 0, stream>>>(Hb1, row_start, csr, isi, iso, b1, Wt2, Hb2, N);
    agg_gemm<64><<<gblocks, 256, 0, stream>>>(Hb2, row_start, csr, isi, iso, b2, Wt3, Hb1, N);
    agg_final<<<ablocks, 256, 0, stream>>>(Hb1, row_start, csr, isi, b3, out, N);
}

// Round 9
// 372.952 us; speedup vs baseline: 1.1455x; 1.1455x over previous
//
#include <hip/hip_runtime.h>
#include <hip/hip_bf16.h>

#define IN_C 128
#define HID_C 128
#define OUT_C 64

typedef unsigned short u16;
typedef unsigned int   u32;
typedef __attribute__((ext_vector_type(8))) short short8;
typedef __attribute__((ext_vector_type(4))) float f32x4;
typedef __attribute__((ext_vector_type(2))) float f32x2;

__device__ __forceinline__ u16 bf16_bits(float x) {
    __hip_bfloat16 h = __float2bfloat16(x);   // RNE
    return *(u16*)&h;
}
__device__ __forceinline__ void split_hi_lo(float a, u16& hi, u16& lo) {
    __hip_bfloat16 h = __float2bfloat16(a);
    float hf = __bfloat162float(h);
    __hip_bfloat16 l = __float2bfloat16(a - hf);
    hi = *(u16*)&h; lo = *(u16*)&l;
}
// acc.{x,y} += unpacked bf16 pair (packed f32 add: 1 VALU inst, same add order)
__device__ __forceinline__ void pk_acc(f32x2& acc, u32 v) {
    f32x2 val;
    val.x = __uint_as_float(v << 16);
    val.y = __uint_as_float(v & 0xffff0000u);
    asm("v_pk_add_f32 %0, %0, %1" : "+v"(acc) : "v"(val));
}

// ============================ CSR build: contention-free radix partition
// Buckets of 256 nodes: bucket = v>>8, K = ceil(N/256). NB partition blocks.

__global__ __launch_bounds__(256)
void part_hist(const int* __restrict__ keys, int* __restrict__ bh,
               int E, int K, int NB) {
    const int b = blockIdx.x;
    extern __shared__ int lh[];                 // K ints
    for (int i = threadIdx.x; i < K; i += 256) lh[i] = 0;
    __syncthreads();
    const int lo = (int)((long long)E * b / NB);
    const int hi = (int)((long long)E * (b + 1) / NB);
    for (int i = lo + threadIdx.x; i < hi; i += 256)
        atomicAdd(&lh[keys[i] >> 8], 1);        // LDS atomic
    __syncthreads();
    for (int k = threadIdx.x; k < K; k += 256)
        bh[k * NB + b] = lh[k];
}

template <bool PACK>
__global__ __launch_bounds__(256)
void part_scatter(const int* __restrict__ keys, const int* __restrict__ other,
                  const int* __restrict__ ofs, u32* __restrict__ out,
                  int E, int K, int NB) {
    const int b = blockIdx.x;
    extern __shared__ int lcur[];               // K ints
    for (int k = threadIdx.x; k < K; k += 256) lcur[k] = ofs[k * NB + b];
    __syncthreads();
    const int lo = (int)((long long)E * b / NB);
    const int hi = (int)((long long)E * (b + 1) / NB);
    for (int i = lo + threadIdx.x; i < hi; i += 256) {
        int key = keys[i];
        int p = atomicAdd(&lcur[key >> 8], 1);  // LDS atomic
        out[p] = PACK ? (((u32)other[i] << 8) | (u32)(key & 255)) : (u32)key;
    }
}

__global__ __launch_bounds__(256)
void bucket_count(const u32* __restrict__ pairs, const int* __restrict__ ofs,
                  int* __restrict__ cnt, int N, int NB, int K, int cap) {
    const int k = blockIdx.x;
    __shared__ int lc[256];
    lc[threadIdx.x] = 0;
    __syncthreads();
    const int s0 = ofs[k * NB];
    const int s1 = (k == K - 1) ? cap : ofs[(k + 1) * NB];
    for (int i = s0 + threadIdx.x; i < s1; i += 256)
        atomicAdd(&lc[pairs[i] & 255], 1);
    __syncthreads();
    const int node = k * 256 + threadIdx.x;
    if (node < N) cnt[node] = lc[threadIdx.x];
}

__global__ __launch_bounds__(256)
void bucket_fill(const u32* __restrict__ pairs, const int* __restrict__ ofs,
                 const int* __restrict__ row_start, int* __restrict__ csr,
                 int N, int NB, int K, int E) {
    const int k = blockIdx.x;
    __shared__ int lcur[256];
    const int node = k * 256 + threadIdx.x;
    lcur[threadIdx.x] = (node < N) ? row_start[node] : 0;
    __syncthreads();
    const int s0 = ofs[k * NB];
    const int s1 = (k == K - 1) ? E : ofs[(k + 1) * NB];
    for (int i = s0 + threadIdx.x; i < s1; i += 256) {
        u32 pr = pairs[i];
        int p = atomicAdd(&lcur[pr & 255], 1);
        csr[p] = (int)(pr >> 8);
    }
}

// ============================ generic scans

__global__ __launch_bounds__(256)
void scan_pass1(const int* __restrict__ in, int* __restrict__ blocksum, int M) {
    const int b = blockIdx.x, t = threadIdx.x;
    const int base = b * 1024 + t * 4;
    int s = 0;
#pragma unroll
    for (int j = 0; j < 4; ++j) {
        int idx = base + j;
        if (idx < M) s += in[idx];
    }
#pragma unroll
    for (int off = 32; off >= 1; off >>= 1) s += __shfl_xor(s, off);
    __shared__ int wsum[4];
    if ((t & 63) == 0) wsum[t >> 6] = s;
    __syncthreads();
    if (t == 0) blocksum[b] = wsum[0] + wsum[1] + wsum[2] + wsum[3];
}

__global__ __launch_bounds__(1024)
void scan_g2(int* __restrict__ a, int nb) {
    __shared__ int s[1024];
    const int t = threadIdx.x;
    int v = (t < nb) ? a[t] : 0;
    s[t] = v;
    __syncthreads();
    for (int off = 1; off < 1024; off <<= 1) {
        int x = (t >= off) ? s[t - off] : 0;
        __syncthreads();
        s[t] += x;
        __syncthreads();
    }
    if (t < nb) a[t] = s[t] - v;    // exclusive
}

__global__ __launch_bounds__(256)
void scan_g3(const int* __restrict__ in, const int* __restrict__ blockoff,
             int* __restrict__ out, int M) {
    __shared__ int ssum[256];
    const int b = blockIdx.x, t = threadIdx.x;
    const int base = b * 1024 + t * 4;
    int c[4];
#pragma unroll
    for (int j = 0; j < 4; ++j) {
        int idx = base + j;
        c[j] = (idx < M) ? in[idx] : 0;
    }
    const int tot = c[0] + c[1] + c[2] + c[3];
    ssum[t] = tot;
    __syncthreads();
    for (int off = 1; off < 256; off <<= 1) {
        int v = (t >= off) ? ssum[t - off] : 0;
        __syncthreads();
        ssum[t] += v;
        __syncthreads();
    }
    int run = blockoff[b] + ssum[t] - tot;
#pragma unroll
    for (int j = 0; j < 4; ++j) {
        int idx = base + j;
        if (idx < M) { out[idx] = run; run += c[j]; }
    }
}

__global__ __launch_bounds__(256)
void scan_pass3n(const int* __restrict__ cnt_in, const int* __restrict__ cnt_out,
                 const int* __restrict__ blockoff, int* __restrict__ row_start,
                 float* __restrict__ iso, float* __restrict__ isi, int N, int E) {
    __shared__ int ssum[256];
    const int b = blockIdx.x, t = threadIdx.x;
    const int base = b * 1024 + t * 4;
    int c[4];
#pragma unroll
    for (int j = 0; j < 4; ++j) {
        int idx = base + j;
        c[j] = (idx < N) ? cnt_in[idx] : 0;
    }
    const int tot = c[0] + c[1] + c[2] + c[3];
    ssum[t] = tot;
    __syncthreads();
    for (int off = 1; off < 256; off <<= 1) {
        int v = (t >= off) ? ssum[t - off] : 0;
        __syncthreads();
        ssum[t] += v;
        __syncthreads();
    }
    int run = blockoff[b] + ssum[t] - tot;
#pragma unroll
    for (int j = 0; j < 4; ++j) {
        int idx = base + j;
        if (idx < N) {
            row_start[idx] = run;
            run += c[j];
            int di = c[j] < 1 ? 1 : c[j];
            int co = cnt_out[idx];
            int dd = co < 1 ? 1 : co;
            isi[idx] = rsqrtf((float)di);
            iso[idx] = rsqrtf((float)dd);
        }
    }
    if (b == 0 && t == 0) row_start[N] = E;
}

// ============================ weight prep: Wt[c][k] = bf16(W[k][c])

__global__ __launch_bounds__(128)
void wt_prep_all(const float* __restrict__ W1, const float* __restrict__ W2,
                 const float* __restrict__ W3, u16* __restrict__ Wt1,
                 u16* __restrict__ Wt2, u16* __restrict__ Wt3) {
    const int b = blockIdx.x, k = threadIdx.x;
    if (b < 128)       Wt1[b * 128 + k] = bf16_bits(W1[k * 128 + b]);
    else if (b < 256)  { int c = b - 128; Wt2[c * 128 + k] = bf16_bits(W2[k * 128 + c]); }
    else               { int c = b - 256; Wt3[c * 128 + k] = bf16_bits(W3[k * 64 + c]); }
}

// ============================ shared MFMA phase
// sAh/sAl: 64 rows x 128 bf16, row stride 136. Wt: [C][128] bf16.
// Layout (HW-verified rounds 6-8): A row=lane&15, k=(lane>>4)*8+j;
// B col=lane&15; D col=lane&15, row=(lane>>4)*4+reg.
template <int C>
__device__ __forceinline__
void mfma_store(const u16* sAh, const u16* sAl, const u16* __restrict__ Wt,
                u16* __restrict__ H, int row0, int N, int t) {
    constexpr int NT = C / 16;
    const int wid = t >> 6, lane = t & 63;
    const int r0 = wid * 16;
    const int arow = r0 + (lane & 15);
    const int kb = (lane >> 4) * 8;

    f32x4 acc[NT];
#pragma unroll
    for (int i = 0; i < NT; ++i) acc[i] = (f32x4){0.f, 0.f, 0.f, 0.f};

    const u16* wbase = Wt + (size_t)(lane & 15) * 128 + kb;

#pragma unroll
    for (int kk = 0; kk < 4; ++kk) {
        short8 ah = *(const short8*)(&sAh[arow * 136 + kk * 32 + kb]);
        short8 al = *(const short8*)(&sAl[arow * 136 + kk * 32 + kb]);
#pragma unroll
        for (int ct = 0; ct < NT; ++ct) {
            short8 bf = *(const short8*)(wbase + ct * 16 * 128 + kk * 32);
            acc[ct] = __builtin_amdgcn_mfma_f32_16x16x32_bf16(ah, bf, acc[ct], 0, 0, 0);
            acc[ct] = __builtin_amdgcn_mfma_f32_16x16x32_bf16(al, bf, acc[ct], 0, 0, 0);
        }
    }

    const int rbase = row0 + r0 + (lane >> 4) * 4;
#pragma unroll
    for (int ct = 0; ct < NT; ++ct) {
        int gcol = ct * 16 + (lane & 15);
#pragma unroll
        for (int r = 0; r < 4; ++r) {
            int grow = rbase + r;
            if (grow < N) H[(size_t)grow * C + gcol] = bf16_bits(acc[ct][r]);
        }
    }
}

// ============================ fused layer-1 GEMM (absorbs x_prep)
// H[N x 128] (bf16) = (features * iso[:,None]) @ W1, via hi/lo split planes.

__global__ __launch_bounds__(256)
void gemm1_fused(const float* __restrict__ X, const float* __restrict__ iso,
                 const u16* __restrict__ Wt, u16* __restrict__ H, int N) {
    __shared__ u16 sAh[64 * 136];
    __shared__ u16 sAl[64 * 136];
    const int t = threadIdx.x;
    const int row0 = blockIdx.x * 64;

    for (int i = t; i < 2048; i += 256) {       // 64 rows x 32 float4-chunks
        int r = i >> 5, kv = (i & 31) << 2;
        int gr = row0 + r;
        if (gr >= N) gr = N - 1;
        float s = iso[gr];
        float4 x = *(const float4*)(X + (size_t)gr * 128 + kv);
        u16 h0, l0, h1, l1, h2, l2, h3, l3;
        split_hi_lo(x.x * s, h0, l0);
        split_hi_lo(x.y * s, h1, l1);
        split_hi_lo(x.z * s, h2, l2);
        split_hi_lo(x.w * s, h3, l3);
        uint2 hp = make_uint2((u32)h0 | ((u32)h1 << 16), (u32)h2 | ((u32)h3 << 16));
        uint2 lp = make_uint2((u32)l0 | ((u32)l1 << 16), (u32)l2 | ((u32)l3 << 16));
        *(uint2*)(&sAh[r * 136 + kv]) = hp;
        *(uint2*)(&sAl[r * 136 + kv]) = lp;
    }
    __syncthreads();
    mfma_store<128>(sAh, sAl, Wt, H, row0, N, t);
}

// ============================ layers 2-3 GEMM: reads Ah/Al planes from global

template <int C>
__global__ __launch_bounds__(256)
void gemm_mfma(const u16* __restrict__ Ah, const u16* __restrict__ Al,
               const u16* __restrict__ Wt, u16* __restrict__ H, int N) {
    __shared__ u16 sAh[64 * 136];
    __shared__ u16 sAl[64 * 136];
    const int t = threadIdx.x;
    const int row0 = blockIdx.x * 64;

    for (int c = t; c < 1024; c += 256) {       // 64 rows x 16 uint4-chunks
        int r = c >> 4, kc = c & 15;
        int gr = row0 + r;
        if (gr >= N) gr = N - 1;
        *(uint4*)(&sAh[r * 136 + kc * 8]) = *(const uint4*)(Ah + (size_t)gr * 128 + kc * 8);
        *(uint4*)(&sAl[r * 136 + kc * 8]) = *(const uint4*)(Al + (size_t)gr * 128 + kc * 8);
    }
    __syncthreads();
    mfma_store<C>(sAh, sAl, Wt, H, row0, N, t);
}

// ============================ gather helper (128-col bf16 rows, MLP-16)

__device__ __forceinline__
f32x2 gather128(const u16* __restrict__ Hin, const int* __restrict__ csr_src,
                int rs, int re, int lane) {
    f32x2 acc; acc.x = 0.f; acc.y = 0.f;
    int e = rs;
    while (e < re) {
        int nloc = re - e;
        if (nloc > 64) nloc = 64;
        int idx = (lane < nloc) ? csr_src[e + lane] : 0;
        int j = 0;
        for (; j + 16 <= nloc; j += 16) {
            u32 v[16];
#pragma unroll
            for (int q = 0; q < 16; ++q) {
                int s = __builtin_amdgcn_readlane(idx, j + q);
                v[q] = *(const u32*)(Hin + (size_t)s * 128 + lane * 2);
            }
#pragma unroll
            for (int q = 0; q < 16; ++q) pk_acc(acc, v[q]);
        }
        for (; j + 4 <= nloc; j += 4) {
            u32 v[4];
#pragma unroll
            for (int q = 0; q < 4; ++q) {
                int s = __builtin_amdgcn_readlane(idx, j + q);
                v[q] = *(const u32*)(Hin + (size_t)s * 128 + lane * 2);
            }
#pragma unroll
            for (int q = 0; q < 4; ++q) pk_acc(acc, v[q]);
        }
        for (; j < nloc; ++j) {
            int s = __builtin_amdgcn_readlane(idx, j);
            pk_acc(acc, *(const u32*)(Hin + (size_t)s * 128 + lane * 2));
        }
        e += nloc;
    }
    return acc;
}

// ============================ aggregation layers 1-2 (one wave per node)
// out = relu(agg*isi + b); emit hi/lo bf16 planes of (out*iso)

__global__ __launch_bounds__(256)
void agg_relu(const u16* __restrict__ H, const int* __restrict__ row_start,
              const int* __restrict__ csr_src, const float* __restrict__ isi,
              const float* __restrict__ iso, const float* __restrict__ bias,
              u16* __restrict__ Ah, u16* __restrict__ Al, int N) {
    const int wid  = (int)((blockIdx.x * (size_t)blockDim.x + threadIdx.x) >> 6);
    const int lane = threadIdx.x & 63;
    if (wid >= N) return;
    const int rs = row_start[wid];
    const int re = row_start[wid + 1];

    f32x2 acc = gather128(H, csr_src, rs, re, lane);

    float2 b = *(const float2*)(bias + lane * 2);
    const float sc = isi[wid], so = iso[wid];
    float o0 = fmaxf(acc.x * sc + b.x, 0.f) * so;
    float o1 = fmaxf(acc.y * sc + b.y, 0.f) * so;
    u16 h0, l0, h1, l1;
    split_hi_lo(o0, h0, l0);
    split_hi_lo(o1, h1, l1);
    ((u32*)Ah)[(size_t)wid * 64 + lane] = (u32)h0 | ((u32)h1 << 16);
    ((u32*)Al)[(size_t)wid * 64 + lane] = (u32)l0 | ((u32)l1 << 16);
}

// ============================ final aggregation: 64-col gather + log_softmax

__global__ __launch_bounds__(256)
void agg_final(const u16* __restrict__ H, const int* __restrict__ row_start,
               const int* __restrict__ csr_src, const float* __restrict__ isi,
               const float* __restrict__ bias, float* __restrict__ Out, int N) {
    const int wid  = (int)((blockIdx.x * (size_t)blockDim.x + threadIdx.x) >> 6);
    const int lane = threadIdx.x & 63;
    if (wid >= N) return;
    const int rs = row_start[wid];
    const int re = row_start[wid + 1];
    const float sc = isi[wid];

    float a = 0.f;
    int e = rs;
    while (e < re) {
        int nloc = re - e;
        if (nloc > 64) nloc = 64;
        int idx = (lane < nloc) ? csr_src[e + lane] : 0;
        int j = 0;
        for (; j + 8 <= nloc; j += 8) {
            u32 v[8];
#pragma unroll
            for (int q = 0; q < 8; ++q) {
                int s = __builtin_amdgcn_readlane(idx, j + q);
                v[q] = H[(size_t)s * 64 + lane];
            }
#pragma unroll
            for (int q = 0; q < 8; ++q) a += __uint_as_float(v[q] << 16);
        }
        for (; j + 4 <= nloc; j += 4) {
            u32 v[4];
#pragma unroll
            for (int q = 0; q < 4; ++q) {
                int s = __builtin_amdgcn_readlane(idx, j + q);
                v[q] = H[(size_t)s * 64 + lane];
            }
#pragma unroll
            for (int q = 0; q < 4; ++q) a += __uint_as_float(v[q] << 16);
        }
        for (; j < nloc; ++j) {
            int s = __builtin_amdgcn_readlane(idx, j);
            a += __uint_as_float((u32)H[(size_t)s * 64 + lane] << 16);
        }
        e += nloc;
    }
    float v = a * sc + bias[lane];
    float m = v;
#pragma unroll
    for (int off = 32; off >= 1; off >>= 1) m = fmaxf(m, __shfl_xor(m, off));
    float ex = expf(v - m);
    float ss = ex;
#pragma unroll
    for (int off = 32; off >= 1; off >>= 1) ss += __shfl_xor(ss, off);
    v = (v - m) - logf(ss);
    Out[(size_t)wid * 64 + lane] = v;
}

// ============================ launch

extern "C" void kernel_launch(void* const* d_in, const int* in_sizes, int n_in,
                              void* d_out, int out_size, void* d_ws, size_t ws_size,
                              hipStream_t stream) {
    const float* features = (const float*)d_in[0];
    const int*   src      = (const int*)d_in[1];
    const int*   dst      = (const int*)d_in[2];
    const float* W1       = (const float*)d_in[3];
    const float* b1       = (const float*)d_in[4];
    const float* W2       = (const float*)d_in[5];
    const float* b2       = (const float*)d_in[6];
    const float* W3       = (const float*)d_in[7];
    const float* b3       = (const float*)d_in[8];
    float*       out      = (float*)d_out;

    const int N  = in_sizes[0] / IN_C;   // 100000
    const int E  = in_sizes[1];          // 1600000
    const int K  = (N + 255) >> 8;       // 391 buckets of 256 nodes
    const int NB = 256;                  // partition blocks
    const int M  = 2 * K * NB;           // concat hist size (dst part | src part)
    const int nbe = (M + 1023) / 1024;
    const int nb  = (N + 1023) / 1024;

    char* ws = (char*)d_ws;
    const size_t SLOT = 400128;          // >= (N+1)*4, 128B-aligned
    int*   cnt_out   = (int*)(ws + 0 * SLOT);
    int*   cnt_in    = (int*)(ws + 1 * SLOT);
    int*   row_start = (int*)(ws + 2 * SLOT);
    float* iso       = (float*)(ws + 3 * SLOT);
    float* isi       = (float*)(ws + 4 * SLOT);
    int*   blocksum  = (int*)(ws + 5 * SLOT);
    int*   eblocksum = blocksum + 2048;
    int*   csr       = (int*)(ws + 6 * SLOT);            // E ints (6.4MB)
    char*  p         = ws + 6 * SLOT + 6400000;
    int*   BH        = (int*)p;                          // 800KB
    int*   OFS       = (int*)(p + 1000000);              // 800KB
    u32*   pairs     = (u32*)(p + 2000000);              // 2E u32 (12.8MB)
    u16*   Hb        = (u16*)(p + 14800000);             // N*128 bf16 (25.6MB)
    u16*   Ah        = (u16*)(p + 40400000);             // N*128 bf16 (25.6MB)
    u16*   Al        = (u16*)(p + 66000000);             // N*128 bf16 (25.6MB)
    u16*   Wt1       = (u16*)(p + 91600000);             // 128*128 bf16
    u16*   Wt2       = Wt1 + 128 * 128;
    u16*   Wt3       = Wt2 + 128 * 128;                  // 64*128 bf16

    const size_t ldsK = (size_t)K * sizeof(int);

    // ---- CSR build: deterministic two-array radix partition ----
    part_hist<<<NB, 256, ldsK, stream>>>(dst, BH,           E, K, NB);
    part_hist<<<NB, 256, ldsK, stream>>>(src, BH + K * NB,  E, K, NB);
    scan_pass1<<<nbe, 256, 0, stream>>>(BH, eblocksum, M);
    scan_g2<<<1, 1024, 0, stream>>>(eblocksum, nbe);
    scan_g3<<<nbe, 256, 0, stream>>>(BH, eblocksum, OFS, M);
    part_scatter<true ><<<NB, 256, ldsK, stream>>>(dst, src, OFS,          pairs, E, K, NB);
    part_scatter<false><<<NB, 256, ldsK, stream>>>(src, src, OFS + K * NB, pairs, E, K, NB);
    bucket_count<<<K, 256, 0, stream>>>(pairs, OFS,          cnt_in,  N, NB, K, E);
    bucket_count<<<K, 256, 0, stream>>>(pairs, OFS + K * NB, cnt_out, N, NB, K, 2 * E);
    scan_pass1<<<nb, 256, 0, stream>>>(cnt_in, blocksum, N);
    scan_g2<<<1, 1024, 0, stream>>>(blocksum, nb);
    scan_pass3n<<<nb, 256, 0, stream>>>(cnt_in, cnt_out, blocksum, row_start, iso, isi, N, E);
    bucket_fill<<<K, 256, 0, stream>>>(pairs, OFS, row_start, csr, N, NB, K, E);

    // ---- weights ----
    wt_prep_all<<<320, 128, 0, stream>>>(W1, W2, W3, Wt1, Wt2, Wt3);

    // ---- 3-layer GCN ----
    const int gblocks = (N + 63) / 64;
    const int ablocks = (int)(((size_t)N * 64 + 255) / 256);

    gemm1_fused<<<gblocks, 256, 0, stream>>>(features, iso, Wt1, Hb, N);
    agg_relu<<<ablocks, 256, 0, stream>>>(Hb, row_start, csr, isi, iso, b1, Ah, Al, N);
    gemm_mfma<128><<<gblocks, 256, 0, stream>>>(Ah, Al, Wt2, Hb, N);
    agg_relu<<<ablocks, 256, 0, stream>>>(Hb, row_start, csr, isi, iso, b2, Ah, Al, N);
    gemm_mfma<64><<<gblocks, 256, 0, stream>>>(Ah, Al, Wt3, Hb, N);
    agg_final<<<ablocks, 256, 0, stream>>>(Hb, row_start, csr, isi, b3, out, N);
}